// Round 8
// baseline (45.898 us; speedup 1.0000x reference)
//
#include <hip/hip_runtime.h>
#include <hip/hip_bf16.h>

#define NUM_SAMPLES 256
#define CH 64
#define IMG_H 512
#define IMG_W 512
#define BATCH 8
#define NBLOCKS (BATCH * NUM_SAMPLES)   // 2048

__device__ __forceinline__ float wave_reduce_sum(float v) {
    v += __shfl_xor(v, 32, 64);
    v += __shfl_xor(v, 16, 64);
    v += __shfl_xor(v, 8, 64);
    v += __shfl_xor(v, 4, 64);
    v += __shfl_xor(v, 2, 64);
    v += __shfl_xor(v, 1, 64);
    return v;
}

// One block of 4 waves per (b, s): wave = (tensor, half-of-neighbors).
//   wid 0: q, nbrs 0-3   wid 1: k, nbrs 0-3
//   wid 2: q, nbrs 4-7   wid 3: k, nbrs 4-7
// Lane = channel. Each block ends with ONE fire-and-forget atomicAdd of its
// scaled partial into d_out (zeroed per call by hipMemsetAsync) — removes the
// second dispatch and its graph gap. Order-variance ~3e-7 << 2.8e-3 threshold.
__global__ void __launch_bounds__(256)
sample_diff_kernel(const float* __restrict__ fq,
                   const float* __restrict__ fk,
                   const int* __restrict__ ids,
                   float* __restrict__ out) {
    const int c    = threadIdx.x & 63;   // channel 0..63
    const int wid  = threadIdx.x >> 6;   // 0..3
    const int tk   = wid & 1;            // 0 = q, 1 = k
    const int half = wid >> 1;           // 0 = neighbors 0-3, 1 = neighbors 4-7
    const int bs   = blockIdx.x;
    const int b    = bs >> 8;
    const int s    = bs & (NUM_SAMPLES - 1);

    const int hi = ids[2 * s + 0];
    const int wi = ids[2 * s + 1];

    const float* __restrict__ src = tk ? fk : fq;

    const size_t HW   = (size_t)IMG_H * IMG_W;
    const size_t base = ((size_t)(b * CH + c)) * HW + (size_t)hi * IMG_W + wi;

    size_t off[4];
    if (half == 0) {
        off[0] = 0;                 // (0,0)
        off[1] = 1;                 // (0,1)
        off[2] = 2;                 // (0,2)
        off[3] = IMG_W;             // (1,0)
    } else {
        off[0] = IMG_W + 2;         // (1,2)
        off[1] = 2 * IMG_W;         // (2,0)
        off[2] = 2 * IMG_W + 1;     // (2,1)
        off[3] = 2 * IMG_W + 2;     // (2,2)
    }

    float ctr = src[base + IMG_W + 1];
    float nb[4];
#pragma unroll
    for (int n = 0; n < 4; ++n) nb[n] = src[base + off[n]];

    // per-neighbor diff + L2 normalization over the 64 channels
    float nv[4];
#pragma unroll
    for (int n = 0; n < 4; ++n) {
        const float d  = nb[n] - ctr;
        const float ss = wave_reduce_sum(d * d);
        nv[n] = d * (1.0f / (sqrtf(ss) + 1e-7f));
    }

    // k-waves publish normalized vectors; q-waves compute |q̂ - k̂|
    __shared__ float kx[2][4][64];       // [half][neighbor][lane]
    __shared__ float sm[2];
    if (tk == 1) {
#pragma unroll
        for (int n = 0; n < 4; ++n) kx[half][n][c] = nv[n];
    }
    __syncthreads();
    if (tk == 0) {
        float acc = 0.0f;
#pragma unroll
        for (int n = 0; n < 4; ++n) acc += fabsf(nv[n] - kx[half][n][c]);
        acc = wave_reduce_sum(acc);
        if (c == 0) sm[half] = acc;
    }
    __syncthreads();
    if (threadIdx.x == 0) {
        // mean over B * C * NUM_SAMPLES * 8 = 1048576 elements
        atomicAdd(out, (sm[0] + sm[1]) * (1.0f / 1048576.0f));
    }
}

extern "C" void kernel_launch(void* const* d_in, const int* in_sizes, int n_in,
                              void* d_out, int out_size, void* d_ws, size_t ws_size,
                              hipStream_t stream) {
    const float* fq  = (const float*)d_in[0];
    const float* fk  = (const float*)d_in[1];
    const int*   ids = (const int*)d_in[2];
    float* out = (float*)d_out;

    hipMemsetAsync(out, 0, sizeof(float), stream);   // graph-capture-safe
    sample_diff_kernel<<<NBLOCKS, 256, 0, stream>>>(fq, fk, ids, out);
}

// Round 9
// 28.390 us; speedup vs baseline: 1.6167x; 1.6167x over previous
//
#include <hip/hip_runtime.h>
#include <hip/hip_bf16.h>

#define NUM_SAMPLES 256
#define CH 64
#define IMG_H 512
#define IMG_W 512
#define BATCH 8
#define NBLOCKS (BATCH * NUM_SAMPLES)   // 2048

__device__ __forceinline__ float wave_reduce_sum(float v) {
    v += __shfl_xor(v, 32, 64);
    v += __shfl_xor(v, 16, 64);
    v += __shfl_xor(v, 8, 64);
    v += __shfl_xor(v, 4, 64);
    v += __shfl_xor(v, 2, 64);
    v += __shfl_xor(v, 1, 64);
    return v;
}

// One block of 4 waves per (b, s): wave = (tensor, half-of-neighbors).
//   wid 0: q, nbrs 0-3   wid 1: k, nbrs 0-3
//   wid 2: q, nbrs 4-7   wid 3: k, nbrs 4-7
// Lane = channel. k-waves publish normalized vectors via LDS; q-waves take
// |q̂ - k̂|. Two-dispatch finish: every single-kernel completion protocol
// (threadfence R2: +94us, single-address atomics R8: +17.5us) regressed on
// cross-XCD coherence serialization.
__global__ void __launch_bounds__(256)
sample_diff_kernel(const float* __restrict__ fq,
                   const float* __restrict__ fk,
                   const int* __restrict__ ids,
                   float* __restrict__ partial) {
    const int c    = threadIdx.x & 63;   // channel 0..63
    const int wid  = threadIdx.x >> 6;   // 0..3
    const int tk   = wid & 1;            // 0 = q, 1 = k
    const int half = wid >> 1;           // 0 = neighbors 0-3, 1 = neighbors 4-7
    const int bs   = blockIdx.x;
    const int b    = bs >> 8;
    const int s    = bs & (NUM_SAMPLES - 1);

    const int hi = ids[2 * s + 0];
    const int wi = ids[2 * s + 1];

    const float* __restrict__ src = tk ? fk : fq;

    const size_t HW   = (size_t)IMG_H * IMG_W;
    const size_t base = ((size_t)(b * CH + c)) * HW + (size_t)hi * IMG_W + wi;

    size_t off[4];
    if (half == 0) {
        off[0] = 0;                 // (0,0)
        off[1] = 1;                 // (0,1)
        off[2] = 2;                 // (0,2)
        off[3] = IMG_W;             // (1,0)
    } else {
        off[0] = IMG_W + 2;         // (1,2)
        off[1] = 2 * IMG_W;         // (2,0)
        off[2] = 2 * IMG_W + 1;     // (2,1)
        off[3] = 2 * IMG_W + 2;     // (2,2)
    }

    const float ctr = src[base + IMG_W + 1];
    float nb[4];
#pragma unroll
    for (int n = 0; n < 4; ++n) nb[n] = src[base + off[n]];

    // per-neighbor diff + L2 normalization over the 64 channels
    float nv[4];
#pragma unroll
    for (int n = 0; n < 4; ++n) {
        const float d  = nb[n] - ctr;
        const float ss = wave_reduce_sum(d * d);
        nv[n] = d * (1.0f / (sqrtf(ss) + 1e-7f));
    }

    // k-waves publish normalized vectors; q-waves compute |q̂ - k̂|
    __shared__ float kx[2][4][64];       // [half][neighbor][lane]
    __shared__ float sm[2];
    if (tk == 1) {
#pragma unroll
        for (int n = 0; n < 4; ++n) kx[half][n][c] = nv[n];
    }
    __syncthreads();
    if (tk == 0) {
        float acc = 0.0f;
#pragma unroll
        for (int n = 0; n < 4; ++n) acc += fabsf(nv[n] - kx[half][n][c]);
        acc = wave_reduce_sum(acc);
        if (c == 0) sm[half] = acc;
    }
    __syncthreads();
    if (threadIdx.x == 0) partial[bs] = sm[0] + sm[1];
}

__global__ void __launch_bounds__(64)
final_reduce_kernel(const float* __restrict__ partial, float* __restrict__ out) {
    const int c = threadIdx.x;
    float v = 0.0f;
#pragma unroll
    for (int i = 0; i < NBLOCKS / 64; ++i)   // 32 per lane, fixed order
        v += partial[i * 64 + c];
    v = wave_reduce_sum(v);
    if (c == 0) {
        // mean over B * C * NUM_SAMPLES * 8 = 1048576 elements
        out[0] = v * (1.0f / 1048576.0f);
    }
}

extern "C" void kernel_launch(void* const* d_in, const int* in_sizes, int n_in,
                              void* d_out, int out_size, void* d_ws, size_t ws_size,
                              hipStream_t stream) {
    const float* fq  = (const float*)d_in[0];
    const float* fk  = (const float*)d_in[1];
    const int*   ids = (const int*)d_in[2];
    float* out     = (float*)d_out;
    float* partial = (float*)d_ws;   // 2048 * 4 = 8 KB

    sample_diff_kernel<<<NBLOCKS, 256, 0, stream>>>(fq, fk, ids, partial);
    final_reduce_kernel<<<1, 64, 0, stream>>>(partial, out);
}